// Round 4
// baseline (434.727 us; speedup 1.0000x reference)
//
#include <hip/hip_runtime.h>
#include <hip/hip_bf16.h>
#include <hip/hip_fp16.h>

#define IN_CH 128
#define NODES_PER_BUCKET 128
#define BUCKET_CAP 5120     // mean 4096, sigma ~64; 16-sigma headroom
#define EDGES_PER_BLOCK 8192

__device__ __forceinline__ float sigmoidf_(float x) { return 1.0f / (1.0f + __expf(-x)); }
__device__ __forceinline__ __half2 u2h(unsigned u) { return __builtin_bit_cast(__half2, u); }
__device__ __forceinline__ unsigned h2u(__half2 h) { return __builtin_bit_cast(unsigned, h); }
__device__ __forceinline__ unsigned packh2(float a, float b) {
    return h2u(__float22half2_rn(make_float2(a, b)));
}

// ---------------- bucketed CSR build ----------------
__global__ __launch_bounds__(256) void k_bucket_scatter(const int* __restrict__ src,
                                                        const int* __restrict__ dst, int E,
                                                        int* __restrict__ bucketCnt, int NB,
                                                        unsigned* __restrict__ pairBuf) {
    __shared__ int hist[1024];
    for (int t = threadIdx.x; t < NB; t += 256) hist[t] = 0;
    __syncthreads();
    int base = blockIdx.x * EDGES_PER_BLOCK;
    int end = min(base + EDGES_PER_BLOCK, E);
    for (int idx = base + threadIdx.x; idx < end; idx += 256)
        atomicAdd(&hist[dst[idx] >> 7], 1);
    __syncthreads();
    for (int t = threadIdx.x; t < NB; t += 256) {
        int c = hist[t];
        hist[t] = c ? atomicAdd(&bucketCnt[t], c) : 0;  // hist becomes running cursor
    }
    __syncthreads();
    for (int idx = base + threadIdx.x; idx < end; idx += 256) {
        int d = dst[idx];
        int b = d >> 7;
        int pos = atomicAdd(&hist[b], 1);
        if (pos < BUCKET_CAP)
            pairBuf[(size_t)b * BUCKET_CAP + pos] = ((unsigned)src[idx] << 7) | (unsigned)(d & 127);
    }
}

__global__ __launch_bounds__(256) void k_bucket_counts(const unsigned* __restrict__ pairBuf,
                                                       const int* __restrict__ bucketCnt,
                                                       int* __restrict__ cnt,
                                                       float* __restrict__ dinv, int n) {
    __shared__ int hist[NODES_PER_BUCKET];
    int b = blockIdx.x;
    if (threadIdx.x < NODES_PER_BUCKET) hist[threadIdx.x] = 0;
    __syncthreads();
    int cb = min(bucketCnt[b], BUCKET_CAP);
    const unsigned* p = pairBuf + (size_t)b * BUCKET_CAP;
    for (int e = threadIdx.x; e < cb; e += 256) atomicAdd(&hist[p[e] & 127], 1);
    __syncthreads();
    if (threadIdx.x < NODES_PER_BUCKET) {
        int node = b * NODES_PER_BUCKET + threadIdx.x;
        if (node < n) {
            int c = hist[threadIdx.x];
            cnt[node] = c;
            dinv[node] = rsqrtf((float)(c + 1));  // +1 self loop
        }
    }
}

__global__ __launch_bounds__(256) void k_bucket_place(const unsigned* __restrict__ pairBuf,
                                                      const int* __restrict__ bucketCnt,
                                                      const int* __restrict__ rowptr,
                                                      int* __restrict__ col, int n) {
    __shared__ int cur[NODES_PER_BUCKET];
    __shared__ int stage[BUCKET_CAP];
    int b = blockIdx.x;
    int first = b * NODES_PER_BUCKET;
    int colBase = rowptr[first];
    if (threadIdx.x < NODES_PER_BUCKET) {
        int node = first + threadIdx.x;
        cur[threadIdx.x] = (node < n) ? (rowptr[node] - colBase) : 0;
    }
    __syncthreads();
    int cb = min(bucketCnt[b], BUCKET_CAP);
    const unsigned* p = pairBuf + (size_t)b * BUCKET_CAP;
    for (int e = threadIdx.x; e < cb; e += 256) {
        unsigned pr = p[e];
        int lpos = atomicAdd(&cur[pr & 127], 1);
        if (lpos < BUCKET_CAP) stage[lpos] = (int)(pr >> 7);
    }
    __syncthreads();
    for (int i = threadIdx.x; i < cb; i += 256) col[colBase + i] = stage[i];
}

// ---------------- rowptr scan ----------------
__global__ void k_scan1(const int* __restrict__ cnt, int n,
                        int* __restrict__ rowptr, int* __restrict__ bsum) {
    __shared__ int sh[256];
    int tid = threadIdx.x;
    int base = blockIdx.x * 1024 + tid * 4;
    int v[4];
    int s = 0;
#pragma unroll
    for (int j = 0; j < 4; j++) {
        int idx = base + j;
        v[j] = (idx < n) ? cnt[idx] : 0;
        s += v[j];
    }
    sh[tid] = s;
    __syncthreads();
    for (int off = 1; off < 256; off <<= 1) {
        int t = (tid >= off) ? sh[tid - off] : 0;
        __syncthreads();
        sh[tid] += t;
        __syncthreads();
    }
    int run = sh[tid] - s;
#pragma unroll
    for (int j = 0; j < 4; j++) {
        int idx = base + j;
        if (idx < n) rowptr[idx] = run;
        run += v[j];
    }
    if (tid == 255) bsum[blockIdx.x] = sh[255];
}

__global__ void k_scan2(int* __restrict__ bsum, int nb) {
    __shared__ int sh[128];
    int tid = threadIdx.x;
    int v = (tid < nb) ? bsum[tid] : 0;
    sh[tid] = v;
    __syncthreads();
    for (int off = 1; off < 128; off <<= 1) {
        int t = (tid >= off) ? sh[tid - off] : 0;
        __syncthreads();
        sh[tid] += t;
        __syncthreads();
    }
    if (tid < nb) bsum[tid] = sh[tid] - v;
}

__global__ void k_scan3(int* __restrict__ rowptr, const int* __restrict__ bsum, int n, int E) {
    int i = blockIdx.x * blockDim.x + threadIdx.x;
    if (i < n) {
        rowptr[i] = rowptr[i] + bsum[i >> 10];
        if (i == 0) rowptr[n] = E;
    }
}

// ---------------- GEMM: Y = (X @ W) * dinv[row], f16 output into channel-half buffers ----
// X: f32 [n,128] (layer1) or f16 half-buffers Xlo/Xhi [n,64] each (layer2).
// W [128,OUTC] f32 row-major. BM=64, BK=16, 256 threads.
template <int OUTC, bool INHALF>
__global__ __launch_bounds__(256) void k_gemm_scale(const float* __restrict__ Xf,
                                                    const unsigned short* __restrict__ Xlo,
                                                    const unsigned short* __restrict__ Xhi,
                                                    const float* __restrict__ W,
                                                    const float* __restrict__ dinv,
                                                    unsigned* __restrict__ Ylo,
                                                    unsigned* __restrict__ Yhi, int n) {
    constexpr int TN = OUTC / 16;  // 8 (128) or 4 (64)
    __shared__ float xs[16][65];
    __shared__ float ws[16 * OUTC];
    int tid = threadIdx.x;
    int row0 = blockIdx.x * 64;
    int tx = tid & 15;
    int ty = tid >> 4;

    float acc[4][TN];
#pragma unroll
    for (int i = 0; i < 4; i++)
#pragma unroll
        for (int j = 0; j < TN; j++) acc[i][j] = 0.0f;

    for (int k0 = 0; k0 < IN_CH; k0 += 16) {
        {
            int r = tid >> 2;
            int kq = (tid & 3) * 4;
            int grow = row0 + r;
            float4 xv = make_float4(0.f, 0.f, 0.f, 0.f);
            if (grow < n) {
                if constexpr (INHALF) {
                    int chb = k0 + kq;
                    const unsigned short* hp = (chb < 64) ? Xlo : Xhi;
                    uint2 xu = *(const uint2*)(hp + (size_t)grow * 64 + (chb & 63));
                    __half2 p0 = u2h(xu.x), p1 = u2h(xu.y);
                    xv = make_float4(__low2float(p0), __high2float(p0), __low2float(p1), __high2float(p1));
                } else {
                    xv = *(const float4*)(Xf + (size_t)grow * IN_CH + k0 + kq);
                }
            }
            xs[kq + 0][r] = xv.x;
            xs[kq + 1][r] = xv.y;
            xs[kq + 2][r] = xv.z;
            xs[kq + 3][r] = xv.w;
        }
        {
            const float4* wsrc = (const float4*)(W + k0 * OUTC);
            float4* wdst = (float4*)ws;
#pragma unroll
            for (int j = 0; j < OUTC / 64; j++) wdst[tid + j * 256] = wsrc[tid + j * 256];
        }
        __syncthreads();
#pragma unroll
        for (int kk = 0; kk < 16; kk++) {
            float a[4];
            *(float4*)a = *(const float4*)&xs[kk][ty * 4];
            float bb[TN];
#pragma unroll
            for (int j = 0; j < TN / 4; j++)
                *(float4*)&bb[j * 4] = *(const float4*)&ws[kk * OUTC + tx * TN + j * 4];
#pragma unroll
            for (int i = 0; i < 4; i++)
#pragma unroll
                for (int j = 0; j < TN; j++) acc[i][j] = fmaf(a[i], bb[j], acc[i][j]);
        }
        __syncthreads();
    }
#pragma unroll
    for (int i = 0; i < 4; i++) {
        int grow = row0 + ty * 4 + i;
        if (grow < n) {
            float dvv = dinv[grow];
            unsigned out_u[TN / 2];
#pragma unroll
            for (int j = 0; j < TN; j += 2) out_u[j / 2] = packh2(acc[i][j] * dvv, acc[i][j + 1] * dvv);
            unsigned* tgt = (tx < 8) ? Ylo : Yhi;
            if constexpr (TN == 8) {
                *(uint4*)(tgt + (size_t)grow * 32 + (tx & 7) * 4) = *(uint4*)out_u;
            } else {
                *(uint2*)(tgt + (size_t)grow * 16 + (tx & 7) * 2) = *(uint2*)out_u;
            }
        }
    }
}

// ---------------- aggregation (channel-split pass) ----------------
// out[d] = act(dinv[d]*(sum_{s in N(d)} y[s] + y[d]) + b), for HC channels.
// One wave per node. Row = HC f16 = HC/4 uint2. Lane group g = lane/LPE serves
// edge i+g; per gather instr EPI edges. col loaded per-group (1 VMEM).
template <int HC, bool OUTHALF>
__global__ __launch_bounds__(256) void k_agg_split(const unsigned* __restrict__ Yh,
                                                   const int* __restrict__ rowptr,
                                                   const int* __restrict__ col,
                                                   const float* __restrict__ dinv,
                                                   const float* __restrict__ biasHalf,
                                                   void* __restrict__ outHalf,
                                                   int n, int outChOff) {
    constexpr int LPE = HC / 4;   // lanes per edge (uint2 = 4 ch): 16 or 8
    constexpr int EPI = 64 / LPE; // edges per gather instr: 4 or 8
    constexpr int RS = HC / 4;    // uint2 per row
    int gid = blockIdx.x * blockDim.x + threadIdx.x;
    int wid = gid >> 6;
    int lane = gid & 63;
    if (wid >= n) return;
    int g = lane / LPE;
    int sub = lane % LPE;
    int s0 = rowptr[wid], s1 = rowptr[wid + 1];
    const uint2* Y2 = (const uint2*)Yh;

    __half2 A0 = u2h(0u), A1 = u2h(0u), B0 = u2h(0u), B1 = u2h(0u);
    // self loop: all groups load own row, keep group 0 only
    {
        uint2 v = Y2[(size_t)wid * RS + sub];
        if (g != 0) { v.x = 0u; v.y = 0u; }
        A0 = __hadd2(A0, u2h(v.x));
        A1 = __hadd2(A1, u2h(v.y));
    }
    int i = s0;
    for (; i + 2 * EPI <= s1; i += 2 * EPI) {
        int c0 = col[i + g];
        int c1 = col[i + EPI + g];
        uint2 va = Y2[(size_t)c0 * RS + sub];
        uint2 vb = Y2[(size_t)c1 * RS + sub];
        A0 = __hadd2(A0, u2h(va.x)); A1 = __hadd2(A1, u2h(va.y));
        B0 = __hadd2(B0, u2h(vb.x)); B1 = __hadd2(B1, u2h(vb.y));
    }
#pragma unroll
    for (int t = 0; t < 2; t++) {
        if (i < s1) {
            int e = i + g;
            int c = col[min(e, s1 - 1)];
            uint2 v = Y2[(size_t)c * RS + sub];
            if (e >= s1) { v.x = 0u; v.y = 0u; }
            A0 = __hadd2(A0, u2h(v.x));
            A1 = __hadd2(A1, u2h(v.y));
            i += EPI;
        }
    }
    A0 = __hadd2(A0, B0);
    A1 = __hadd2(A1, B1);
    // cross-group reduce
#pragma unroll
    for (int m = LPE; m < 64; m <<= 1) {
        A0 = __hadd2(A0, u2h((unsigned)__shfl_xor((int)h2u(A0), m, 64)));
        A1 = __hadd2(A1, u2h((unsigned)__shfl_xor((int)h2u(A1), m, 64)));
    }
    if (lane < LPE) {
        float dv = dinv[wid];
        float4 bv = *(const float4*)&biasHalf[sub * 4];
        float o0 = sigmoidf_(__low2float(A0) * dv + bv.x);
        float o1 = sigmoidf_(__high2float(A0) * dv + bv.y);
        float o2 = sigmoidf_(__low2float(A1) * dv + bv.z);
        float o3 = sigmoidf_(__high2float(A1) * dv + bv.w);
        if constexpr (OUTHALF) {
            uint2 o;
            o.x = packh2(o0, o1);
            o.y = packh2(o2, o3);
            ((uint2*)outHalf)[(size_t)wid * RS + sub] = o;
        } else {
            *(float4*)((float*)outHalf + (size_t)wid * 64 + outChOff + sub * 4) =
                make_float4(o0, o1, o2, o3);
        }
    }
}

extern "C" void kernel_launch(void* const* d_in, const int* in_sizes, int n_in,
                              void* d_out, int out_size, void* d_ws, size_t ws_size,
                              hipStream_t stream) {
    const float* x  = (const float*)d_in[0];
    const int* eidx = (const int*)d_in[1];
    const float* W1 = (const float*)d_in[2];
    const float* b1 = (const float*)d_in[3];
    const float* W2 = (const float*)d_in[4];
    const float* b2 = (const float*)d_in[5];
    float* out = (float*)d_out;

    int n = in_sizes[0] / IN_CH;
    int E = in_sizes[1] / 2;
    const int* srcv = eidx;
    const int* dstv = eidx + E;
    int NB = (n + NODES_PER_BUCKET - 1) / NODES_PER_BUCKET;  // 782

    char* w = (char*)d_ws;
    auto alloc = [&](size_t bytes) {
        char* p = w;
        w += (bytes + 255) & ~(size_t)255;
        return p;
    };
    int* bucketCnt    = (int*)alloc((size_t)NB * 4);
    unsigned* pairBuf = (unsigned*)alloc((size_t)NB * BUCKET_CAP * 4);
    int* cnt          = (int*)alloc((size_t)n * 4);
    int* rowptr       = (int*)alloc(((size_t)n + 1) * 4);
    int* bsum         = (int*)alloc(4096);
    float* dinv       = (float*)alloc((size_t)n * 4);
    int* col          = (int*)alloc((size_t)E * 4);
    unsigned* y_lo    = (unsigned*)alloc((size_t)n * 64 * 2);  // f16 [n][64]
    unsigned* y_hi    = (unsigned*)alloc((size_t)n * 64 * 2);
    unsigned* h_lo    = (unsigned*)alloc((size_t)n * 64 * 2);
    unsigned* h_hi    = (unsigned*)alloc((size_t)n * 64 * 2);
    unsigned* y2_lo   = (unsigned*)alloc((size_t)n * 32 * 2);  // f16 [n][32]
    unsigned* y2_hi   = (unsigned*)alloc((size_t)n * 32 * 2);

    hipMemsetAsync(bucketCnt, 0, (size_t)NB * 4, stream);
    int nblk = (E + EDGES_PER_BLOCK - 1) / EDGES_PER_BLOCK;
    k_bucket_scatter<<<nblk, 256, 0, stream>>>(srcv, dstv, E, bucketCnt, NB, pairBuf);
    k_bucket_counts<<<NB, 256, 0, stream>>>(pairBuf, bucketCnt, cnt, dinv, n);
    int nb = (n + 1023) / 1024;
    k_scan1<<<nb, 256, 0, stream>>>(cnt, n, rowptr, bsum);
    k_scan2<<<1, 128, 0, stream>>>(bsum, nb);
    k_scan3<<<(n + 255) / 256, 256, 0, stream>>>(rowptr, bsum, n, E);
    k_bucket_place<<<NB, 256, 0, stream>>>(pairBuf, bucketCnt, rowptr, col, n);

    int gemmGrid = (n + 63) / 64;
    int aggGrid = (n + 3) / 4;  // 4 waves (nodes) per 256-thread block

    // layer 1
    k_gemm_scale<128, false><<<gemmGrid, 256, 0, stream>>>(x, nullptr, nullptr, W1, dinv, y_lo, y_hi, n);
    k_agg_split<64, true><<<aggGrid, 256, 0, stream>>>(y_lo, rowptr, col, dinv, b1, h_lo, n, 0);
    k_agg_split<64, true><<<aggGrid, 256, 0, stream>>>(y_hi, rowptr, col, dinv, b1 + 64, h_hi, n, 0);
    // layer 2
    k_gemm_scale<64, true><<<gemmGrid, 256, 0, stream>>>(nullptr, (const unsigned short*)h_lo,
                                                         (const unsigned short*)h_hi, W2, dinv,
                                                         y2_lo, y2_hi, n);
    k_agg_split<32, false><<<aggGrid, 256, 0, stream>>>(y2_lo, rowptr, col, dinv, b2, out, n, 0);
    k_agg_split<32, false><<<aggGrid, 256, 0, stream>>>(y2_hi, rowptr, col, dinv, b2 + 32, out, n, 32);
}

// Round 5
// 328.508 us; speedup vs baseline: 1.3233x; 1.3233x over previous
//
#include <hip/hip_runtime.h>
#include <hip/hip_bf16.h>
#include <hip/hip_fp16.h>

#define IN_CH 128
#define NODES_PER_BUCKET 128
#define BUCKET_CAP 5120     // mean 4096, sigma ~64; 16-sigma headroom
#define EDGES_PER_BLOCK 8192

__device__ __forceinline__ float sigmoidf_(float x) { return 1.0f / (1.0f + __expf(-x)); }
__device__ __forceinline__ __half2 u2h(unsigned u) { return __builtin_bit_cast(__half2, u); }
__device__ __forceinline__ unsigned h2u(__half2 h) { return __builtin_bit_cast(unsigned, h); }
__device__ __forceinline__ unsigned packh2(float a, float b) {
    return h2u(__float22half2_rn(make_float2(a, b)));
}

// ---------------- bucketed CSR build ----------------
__global__ __launch_bounds__(256) void k_bucket_scatter(const int* __restrict__ src,
                                                        const int* __restrict__ dst, int E,
                                                        int* __restrict__ bucketCnt, int NB,
                                                        unsigned* __restrict__ pairBuf) {
    __shared__ int hist[1024];
    for (int t = threadIdx.x; t < NB; t += 256) hist[t] = 0;
    __syncthreads();
    int base = blockIdx.x * EDGES_PER_BLOCK;
    int end = min(base + EDGES_PER_BLOCK, E);
    for (int idx = base + threadIdx.x; idx < end; idx += 256)
        atomicAdd(&hist[dst[idx] >> 7], 1);
    __syncthreads();
    for (int t = threadIdx.x; t < NB; t += 256) {
        int c = hist[t];
        hist[t] = c ? atomicAdd(&bucketCnt[t], c) : 0;  // hist becomes running cursor
    }
    __syncthreads();
    for (int idx = base + threadIdx.x; idx < end; idx += 256) {
        int d = dst[idx];
        int b = d >> 7;
        int pos = atomicAdd(&hist[b], 1);
        if (pos < BUCKET_CAP)
            pairBuf[(size_t)b * BUCKET_CAP + pos] = ((unsigned)src[idx] << 7) | (unsigned)(d & 127);
    }
}

__global__ __launch_bounds__(256) void k_bucket_counts(const unsigned* __restrict__ pairBuf,
                                                       const int* __restrict__ bucketCnt,
                                                       int* __restrict__ cnt,
                                                       float* __restrict__ dinv, int n) {
    __shared__ int hist[NODES_PER_BUCKET];
    int b = blockIdx.x;
    if (threadIdx.x < NODES_PER_BUCKET) hist[threadIdx.x] = 0;
    __syncthreads();
    int cb = min(bucketCnt[b], BUCKET_CAP);
    const unsigned* p = pairBuf + (size_t)b * BUCKET_CAP;
    for (int e = threadIdx.x; e < cb; e += 256) atomicAdd(&hist[p[e] & 127], 1);
    __syncthreads();
    if (threadIdx.x < NODES_PER_BUCKET) {
        int node = b * NODES_PER_BUCKET + threadIdx.x;
        if (node < n) {
            int c = hist[threadIdx.x];
            cnt[node] = c;
            dinv[node] = rsqrtf((float)(c + 1));  // +1 self loop
        }
    }
}

__global__ __launch_bounds__(256) void k_bucket_place(const unsigned* __restrict__ pairBuf,
                                                      const int* __restrict__ bucketCnt,
                                                      const int* __restrict__ rowptr,
                                                      int* __restrict__ col, int n) {
    __shared__ int cur[NODES_PER_BUCKET];
    __shared__ int stage[BUCKET_CAP];
    int b = blockIdx.x;
    int first = b * NODES_PER_BUCKET;
    int colBase = rowptr[first];
    if (threadIdx.x < NODES_PER_BUCKET) {
        int node = first + threadIdx.x;
        cur[threadIdx.x] = (node < n) ? (rowptr[node] - colBase) : 0;
    }
    __syncthreads();
    int cb = min(bucketCnt[b], BUCKET_CAP);
    const unsigned* p = pairBuf + (size_t)b * BUCKET_CAP;
    for (int e = threadIdx.x; e < cb; e += 256) {
        unsigned pr = p[e];
        int lpos = atomicAdd(&cur[pr & 127], 1);
        if (lpos < BUCKET_CAP) stage[lpos] = (int)(pr >> 7);
    }
    __syncthreads();
    for (int i = threadIdx.x; i < cb; i += 256) col[colBase + i] = stage[i];
}

// ---------------- rowptr scan ----------------
__global__ void k_scan1(const int* __restrict__ cnt, int n,
                        int* __restrict__ rowptr, int* __restrict__ bsum) {
    __shared__ int sh[256];
    int tid = threadIdx.x;
    int base = blockIdx.x * 1024 + tid * 4;
    int v[4];
    int s = 0;
#pragma unroll
    for (int j = 0; j < 4; j++) {
        int idx = base + j;
        v[j] = (idx < n) ? cnt[idx] : 0;
        s += v[j];
    }
    sh[tid] = s;
    __syncthreads();
    for (int off = 1; off < 256; off <<= 1) {
        int t = (tid >= off) ? sh[tid - off] : 0;
        __syncthreads();
        sh[tid] += t;
        __syncthreads();
    }
    int run = sh[tid] - s;
#pragma unroll
    for (int j = 0; j < 4; j++) {
        int idx = base + j;
        if (idx < n) rowptr[idx] = run;
        run += v[j];
    }
    if (tid == 255) bsum[blockIdx.x] = sh[255];
}

__global__ void k_scan2(int* __restrict__ bsum, int nb) {
    __shared__ int sh[128];
    int tid = threadIdx.x;
    int v = (tid < nb) ? bsum[tid] : 0;
    sh[tid] = v;
    __syncthreads();
    for (int off = 1; off < 128; off <<= 1) {
        int t = (tid >= off) ? sh[tid - off] : 0;
        __syncthreads();
        sh[tid] += t;
        __syncthreads();
    }
    if (tid < nb) bsum[tid] = sh[tid] - v;
}

__global__ void k_scan3(int* __restrict__ rowptr, const int* __restrict__ bsum, int n, int E) {
    int i = blockIdx.x * blockDim.x + threadIdx.x;
    if (i < n) {
        rowptr[i] = rowptr[i] + bsum[i >> 10];
        if (i == 0) rowptr[n] = E;
    }
}

// ---------------- GEMM: Y = (X @ W) * dinv[row], output f16 ----------------
// X [n,128] (f32 or f16), W [128,OUTC] f32 row-major. BM=64, BK=16, 256 threads.
template <int OUTC, bool INHALF>
__global__ __launch_bounds__(256) void k_gemm_scale(const void* __restrict__ Xv,
                                                    const float* __restrict__ W,
                                                    const float* __restrict__ dinv,
                                                    unsigned* __restrict__ Y, int n) {
    constexpr int TN = OUTC / 16;  // 8 (128) or 4 (64)
    __shared__ float xs[16][65];
    __shared__ float ws[16 * OUTC];
    int tid = threadIdx.x;
    int row0 = blockIdx.x * 64;
    int tx = tid & 15;
    int ty = tid >> 4;

    float acc[4][TN];
#pragma unroll
    for (int i = 0; i < 4; i++)
#pragma unroll
        for (int j = 0; j < TN; j++) acc[i][j] = 0.0f;

    for (int k0 = 0; k0 < IN_CH; k0 += 16) {
        {
            int r = tid >> 2;
            int kq = (tid & 3) * 4;
            int grow = row0 + r;
            float4 xv = make_float4(0.f, 0.f, 0.f, 0.f);
            if (grow < n) {
                if constexpr (INHALF) {
                    uint2 xu = *(const uint2*)((const unsigned short*)Xv + (size_t)grow * IN_CH + k0 + kq);
                    __half2 p0 = u2h(xu.x), p1 = u2h(xu.y);
                    xv = make_float4(__low2float(p0), __high2float(p0), __low2float(p1), __high2float(p1));
                } else {
                    xv = *(const float4*)((const float*)Xv + (size_t)grow * IN_CH + k0 + kq);
                }
            }
            xs[kq + 0][r] = xv.x;
            xs[kq + 1][r] = xv.y;
            xs[kq + 2][r] = xv.z;
            xs[kq + 3][r] = xv.w;
        }
        {
            const float4* wsrc = (const float4*)(W + k0 * OUTC);
            float4* wdst = (float4*)ws;
#pragma unroll
            for (int j = 0; j < OUTC / 64; j++) wdst[tid + j * 256] = wsrc[tid + j * 256];
        }
        __syncthreads();
#pragma unroll
        for (int kk = 0; kk < 16; kk++) {
            float a[4];
            *(float4*)a = *(const float4*)&xs[kk][ty * 4];
            float bb[TN];
#pragma unroll
            for (int j = 0; j < TN / 4; j++)
                *(float4*)&bb[j * 4] = *(const float4*)&ws[kk * OUTC + tx * TN + j * 4];
#pragma unroll
            for (int i = 0; i < 4; i++)
#pragma unroll
                for (int j = 0; j < TN; j++) acc[i][j] = fmaf(a[i], bb[j], acc[i][j]);
        }
        __syncthreads();
    }
#pragma unroll
    for (int i = 0; i < 4; i++) {
        int grow = row0 + ty * 4 + i;
        if (grow < n) {
            float dvv = dinv[grow];
            unsigned out_u[TN / 2];
#pragma unroll
            for (int j = 0; j < TN; j += 2) out_u[j / 2] = packh2(acc[i][j] * dvv, acc[i][j + 1] * dvv);
            unsigned* dstp = Y + (size_t)grow * (OUTC / 2) + tx * (TN / 2);
            if constexpr (TN == 8) {
                *(uint4*)dstp = *(uint4*)out_u;
            } else {
                *(uint2*)dstp = *(uint2*)out_u;
            }
        }
    }
}

// ---------------- aggregation: out = act(dinv[d]*(sum y[s] + y[d]) + b) ----------------
// One wave per node. Row = C f16 = C/8 uint4. Lane group g (of LPE lanes) serves
// edge i+g: each gather instr covers EPI edges at 16 B/lane. col index fetched
// per-lane as col[i+g] (one dword VMEM per EPI edges, zero select overhead).
// VMEM per 8 edges: C=128 -> 4 instrs, C=64 -> 2 instrs.
template <int C, bool OUTHALF>
__global__ __launch_bounds__(256) void k_agg(const uint4* __restrict__ Y4,
                                             const int* __restrict__ rowptr,
                                             const int* __restrict__ col,
                                             const float* __restrict__ dinv,
                                             const float* __restrict__ bias,
                                             void* __restrict__ out, int n) {
    constexpr int LPE = C / 8;     // lanes per row: 16 (C=128) or 8 (C=64)
    constexpr int EPI = 64 / LPE;  // edges per gather instr: 4 or 8
    constexpr int RS = C / 8;      // uint4 per row
    int gid = blockIdx.x * blockDim.x + threadIdx.x;
    int wid = gid >> 6;
    int lane = gid & 63;
    if (wid >= n) return;
    int g = lane / LPE;
    int sub = lane % LPE;
    int s0 = rowptr[wid], s1 = rowptr[wid + 1];

    __half2 A0 = u2h(0u), A1 = u2h(0u), A2 = u2h(0u), A3 = u2h(0u);
    __half2 B0 = u2h(0u), B1 = u2h(0u), B2 = u2h(0u), B3 = u2h(0u);
    // self loop: group 0 only
    {
        uint4 v = Y4[(size_t)wid * RS + sub];
        if (g != 0) { v.x = v.y = v.z = v.w = 0u; }
        A0 = __hadd2(A0, u2h(v.x)); A1 = __hadd2(A1, u2h(v.y));
        A2 = __hadd2(A2, u2h(v.z)); A3 = __hadd2(A3, u2h(v.w));
    }
    int i = s0;
    for (; i + 2 * EPI <= s1; i += 2 * EPI) {
        int ca = col[i + g];
        int cb = col[i + EPI + g];
        uint4 va = Y4[(size_t)ca * RS + sub];
        uint4 vb = Y4[(size_t)cb * RS + sub];
        A0 = __hadd2(A0, u2h(va.x)); A1 = __hadd2(A1, u2h(va.y));
        A2 = __hadd2(A2, u2h(va.z)); A3 = __hadd2(A3, u2h(va.w));
        B0 = __hadd2(B0, u2h(vb.x)); B1 = __hadd2(B1, u2h(vb.y));
        B2 = __hadd2(B2, u2h(vb.z)); B3 = __hadd2(B3, u2h(vb.w));
    }
    // masked tail (<= 2 iterations of EPI edges)
    for (; i < s1; i += EPI) {
        int e = i + g;
        int c = col[min(e, s1 - 1)];
        uint4 v = Y4[(size_t)c * RS + sub];
        if (e >= s1) { v.x = v.y = v.z = v.w = 0u; }
        A0 = __hadd2(A0, u2h(v.x)); A1 = __hadd2(A1, u2h(v.y));
        A2 = __hadd2(A2, u2h(v.z)); A3 = __hadd2(A3, u2h(v.w));
    }
    A0 = __hadd2(A0, B0); A1 = __hadd2(A1, B1);
    A2 = __hadd2(A2, B2); A3 = __hadd2(A3, B3);
    // cross-group reduce (groups share sub)
#pragma unroll
    for (int m = LPE; m < 64; m <<= 1) {
        A0 = __hadd2(A0, u2h((unsigned)__shfl_xor((int)h2u(A0), m, 64)));
        A1 = __hadd2(A1, u2h((unsigned)__shfl_xor((int)h2u(A1), m, 64)));
        A2 = __hadd2(A2, u2h((unsigned)__shfl_xor((int)h2u(A2), m, 64)));
        A3 = __hadd2(A3, u2h((unsigned)__shfl_xor((int)h2u(A3), m, 64)));
    }
    if (lane < LPE) {
        float dv = dinv[wid];
        float f[8];
        f[0] = __low2float(A0); f[1] = __high2float(A0);
        f[2] = __low2float(A1); f[3] = __high2float(A1);
        f[4] = __low2float(A2); f[5] = __high2float(A2);
        f[6] = __low2float(A3); f[7] = __high2float(A3);
        float4 bv0 = *(const float4*)&bias[sub * 8];
        float4 bv1 = *(const float4*)&bias[sub * 8 + 4];
        float o[8];
        o[0] = sigmoidf_(f[0] * dv + bv0.x); o[1] = sigmoidf_(f[1] * dv + bv0.y);
        o[2] = sigmoidf_(f[2] * dv + bv0.z); o[3] = sigmoidf_(f[3] * dv + bv0.w);
        o[4] = sigmoidf_(f[4] * dv + bv1.x); o[5] = sigmoidf_(f[5] * dv + bv1.y);
        o[6] = sigmoidf_(f[6] * dv + bv1.z); o[7] = sigmoidf_(f[7] * dv + bv1.w);
        if constexpr (OUTHALF) {
            uint4 ov;
            ov.x = packh2(o[0], o[1]); ov.y = packh2(o[2], o[3]);
            ov.z = packh2(o[4], o[5]); ov.w = packh2(o[6], o[7]);
            ((uint4*)out)[(size_t)wid * RS + sub] = ov;
        } else {
            float* op = (float*)out + (size_t)wid * C + sub * 8;
            *(float4*)op = make_float4(o[0], o[1], o[2], o[3]);
            *(float4*)(op + 4) = make_float4(o[4], o[5], o[6], o[7]);
        }
    }
}

extern "C" void kernel_launch(void* const* d_in, const int* in_sizes, int n_in,
                              void* d_out, int out_size, void* d_ws, size_t ws_size,
                              hipStream_t stream) {
    const float* x  = (const float*)d_in[0];
    const int* eidx = (const int*)d_in[1];
    const float* W1 = (const float*)d_in[2];
    const float* b1 = (const float*)d_in[3];
    const float* W2 = (const float*)d_in[4];
    const float* b2 = (const float*)d_in[5];
    float* out = (float*)d_out;

    int n = in_sizes[0] / IN_CH;
    int E = in_sizes[1] / 2;
    const int* srcv = eidx;
    const int* dstv = eidx + E;
    int NB = (n + NODES_PER_BUCKET - 1) / NODES_PER_BUCKET;  // 782

    char* w = (char*)d_ws;
    auto alloc = [&](size_t bytes) {
        char* p = w;
        w += (bytes + 255) & ~(size_t)255;
        return p;
    };
    int* bucketCnt    = (int*)alloc((size_t)NB * 4);
    unsigned* pairBuf = (unsigned*)alloc((size_t)NB * BUCKET_CAP * 4);
    int* cnt          = (int*)alloc((size_t)n * 4);
    int* rowptr       = (int*)alloc(((size_t)n + 1) * 4);
    int* bsum         = (int*)alloc(4096);
    float* dinv       = (float*)alloc((size_t)n * 4);
    int* col          = (int*)alloc((size_t)E * 4);
    unsigned* y       = (unsigned*)alloc((size_t)n * IN_CH * 2);  // f16 [n][128]; reused for y2
    unsigned* h       = (unsigned*)alloc((size_t)n * IN_CH * 2);  // f16 [n][128]

    hipMemsetAsync(bucketCnt, 0, (size_t)NB * 4, stream);
    int nblk = (E + EDGES_PER_BLOCK - 1) / EDGES_PER_BLOCK;
    k_bucket_scatter<<<nblk, 256, 0, stream>>>(srcv, dstv, E, bucketCnt, NB, pairBuf);
    k_bucket_counts<<<NB, 256, 0, stream>>>(pairBuf, bucketCnt, cnt, dinv, n);
    int nb = (n + 1023) / 1024;
    k_scan1<<<nb, 256, 0, stream>>>(cnt, n, rowptr, bsum);
    k_scan2<<<1, 128, 0, stream>>>(bsum, nb);
    k_scan3<<<(n + 255) / 256, 256, 0, stream>>>(rowptr, bsum, n, E);
    k_bucket_place<<<NB, 256, 0, stream>>>(pairBuf, bucketCnt, rowptr, col, n);

    int gemmGrid = (n + 63) / 64;
    int aggGrid = (n + 3) / 4;  // 4 waves (nodes) per 256-thread block

    // layer 1
    k_gemm_scale<128, false><<<gemmGrid, 256, 0, stream>>>(x, W1, dinv, y, n);
    k_agg<128, true><<<aggGrid, 256, 0, stream>>>((const uint4*)y, rowptr, col, dinv, b1, h, n);
    // layer 2 (y buffer reused for y2)
    k_gemm_scale<64, true><<<gemmGrid, 256, 0, stream>>>(h, W2, dinv, y, n);
    k_agg<64, false><<<aggGrid, 256, 0, stream>>>((const uint4*)y, rowptr, col, dinv, b2, out, n);
}